// Round 17
// baseline (2873.944 us; speedup 1.0000x reference)
//
#include <hip/hip_runtime.h>
#include <cstdint>
#include <cstddef>
#include <math.h>

typedef unsigned short u16;
typedef __attribute__((ext_vector_type(4))) float f32x4;
typedef __attribute__((ext_vector_type(8))) short short8;
typedef __attribute__((ext_vector_type(4))) short short4v;

__device__ __forceinline__ float b2f(u16 u) {
    union { unsigned int i; float f; } v; v.i = ((unsigned int)u) << 16; return v.f;
}
__device__ __forceinline__ u16 f2b(float f) {
    union { float f; unsigned int i; } v; v.f = f;
    unsigned int i = v.i;
    return (u16)((i + 0x7FFFu + ((i >> 16) & 1u)) >> 16);
}
// exact truncation-based 3-way split: a = h + m + l' with |err| <= 2^-24|a|
__device__ __forceinline__ void split3t(float a, short& h, short& m, short& l) {
    union { float f; unsigned int u; } va, vh, v1, vm, v2;
    va.f = a;
    vh.u = va.u & 0xFFFF0000u;
    float r1 = a - vh.f;                 // exact
    v1.f = r1;
    vm.u = v1.u & 0xFFFF0000u;
    float r2 = r1 - vm.f;                // exact
    v2.f = r2;
    h = (short)(vh.u >> 16);
    m = (short)(vm.u >> 16);
    l = (short)(v2.u >> 16);
}
__device__ __forceinline__ float gelu_f(float x) {
    float x3 = x * x * x;
    float y = 0.7978845608028654f * (x + 0.044715f * x3);
    float ya = fminf(fabsf(y), 15.f);
    float e = expf(-2.f * ya);
    float t = (1.f - e) / (1.f + e);
    t = copysignf(t, y);
    return 0.5f * x * (1.f + t);
}
// async global->LDS, 16 bytes per lane; LDS dest must be linear (wave base + lane*16)
__device__ __forceinline__ void gld16(const u16* g, u16* l)
{
    __builtin_amdgcn_global_load_lds(
        (const __attribute__((address_space(1))) void*)(g),
        (__attribute__((address_space(3))) void*)(l),
        16, 0, 0);
}

// ================= f32-faithful GEMM via 6-term bf16x3 MFMA emulation =================
struct EGemmP {
    const float* A; int lda; long aSo, aSi; int aDiv;
    const float* B; int ldb; long bSo, bSi; int bDiv;
    float* C; int ldc; long cSo, cSi; int cDiv;
    const float* bias;
    const float* resid;   // EPI 1,2
    const float* fus;     // EPI 2
    int K;
};

// EPI: 0 = store f32; 1 = v + resid; 2 = resid + sigmoid(v)*fus
template<int EPI, int WM, int WN, int MF, int NF>
__global__ __launch_bounds__(256)
void gemm_emu(EGemmP p)
{
    constexpr int TM = WM * MF * 16;
    constexpr int TN = WN * NF * 16;
    constexpr int TK = 32;
    __shared__ u16 Ah[TM * TK], Am[TM * TK], Al[TM * TK];
    __shared__ u16 Bh[TN * TK], Bm[TN * TK], Bl[TN * TK];
    const int tid = threadIdx.x;
    const int z = blockIdx.z;
    const float* Ab = p.A + (long)(z / p.aDiv) * p.aSo + (long)(z % p.aDiv) * p.aSi
                      + (long)blockIdx.x * TM * p.lda;
    const float* Bb = p.B + (long)(z / p.bDiv) * p.bSo + (long)(z % p.bDiv) * p.bSi
                      + (long)blockIdx.y * TN * p.ldb;
    const int lane = tid & 63;
    const int wv = tid >> 6;
    const int wm = wv / WN;
    const int wn = wv % WN;
    const int kg = lane >> 4;
    const int l16 = lane & 15;
    f32x4 acc[MF][NF];
#pragma unroll
    for (int m = 0; m < MF; ++m)
#pragma unroll
        for (int n = 0; n < NF; ++n)
            acc[m][n] = (f32x4){0.f, 0.f, 0.f, 0.f};

    for (int k0 = 0; k0 < p.K; k0 += TK) {
#pragma unroll
        for (int i = 0; i < (TM * TK) / 1024; ++i) {
            int e = i * 256 + tid;
            int r = e >> 3;
            int c = (e & 7) * 4;
            f32x4 a = *(const f32x4*)&Ab[(long)r * p.lda + k0 + c];
            short4v h, m, l;
#pragma unroll
            for (int j = 0; j < 4; ++j) {
                short th, tm2, tl2;
                split3t(a[j], th, tm2, tl2);
                h[j] = th; m[j] = tm2; l[j] = tl2;
            }
            *(short4v*)&Ah[r * TK + c] = h;
            *(short4v*)&Am[r * TK + c] = m;
            *(short4v*)&Al[r * TK + c] = l;
        }
#pragma unroll
        for (int i = 0; i < (TN * TK) / 1024; ++i) {
            int e = i * 256 + tid;
            int r = e >> 3;
            int c = (e & 7) * 4;
            f32x4 a = *(const f32x4*)&Bb[(long)r * p.ldb + k0 + c];
            short4v h, m, l;
#pragma unroll
            for (int j = 0; j < 4; ++j) {
                short th, tm2, tl2;
                split3t(a[j], th, tm2, tl2);
                h[j] = th; m[j] = tm2; l[j] = tl2;
            }
            *(short4v*)&Bh[r * TK + c] = h;
            *(short4v*)&Bm[r * TK + c] = m;
            *(short4v*)&Bl[r * TK + c] = l;
        }
        __syncthreads();
        short8 ah[MF], am[MF], al[MF], bh[NF], bm[NF], bl[NF];
#pragma unroll
        for (int m = 0; m < MF; ++m) {
            int ro = (wm * MF * 16 + m * 16 + l16) * TK + kg * 8;
            ah[m] = *(const short8*)&Ah[ro];
            am[m] = *(const short8*)&Am[ro];
            al[m] = *(const short8*)&Al[ro];
        }
#pragma unroll
        for (int n = 0; n < NF; ++n) {
            int ro = (wn * NF * 16 + n * 16 + l16) * TK + kg * 8;
            bh[n] = *(const short8*)&Bh[ro];
            bm[n] = *(const short8*)&Bm[ro];
            bl[n] = *(const short8*)&Bl[ro];
        }
#pragma unroll
        for (int m = 0; m < MF; ++m)
#pragma unroll
            for (int n = 0; n < NF; ++n) {
                f32x4 a = acc[m][n];
                a = __builtin_amdgcn_mfma_f32_16x16x32_bf16(al[m], bh[n], a, 0, 0, 0);
                a = __builtin_amdgcn_mfma_f32_16x16x32_bf16(ah[m], bl[n], a, 0, 0, 0);
                a = __builtin_amdgcn_mfma_f32_16x16x32_bf16(am[m], bm[n], a, 0, 0, 0);
                a = __builtin_amdgcn_mfma_f32_16x16x32_bf16(am[m], bh[n], a, 0, 0, 0);
                a = __builtin_amdgcn_mfma_f32_16x16x32_bf16(ah[m], bm[n], a, 0, 0, 0);
                a = __builtin_amdgcn_mfma_f32_16x16x32_bf16(ah[m], bh[n], a, 0, 0, 0);
                acc[m][n] = a;
            }
        __syncthreads();
    }
    const long cbase = (long)(z / p.cDiv) * p.cSo + (long)(z % p.cDiv) * p.cSi;
#pragma unroll
    for (int m = 0; m < MF; ++m)
#pragma unroll
        for (int n = 0; n < NF; ++n) {
            const int colt = blockIdx.y * TN + wn * NF * 16 + n * 16 + l16;
            float bv = p.bias ? p.bias[colt] : 0.f;
#pragma unroll
            for (int r = 0; r < 4; ++r) {
                const int rowt = blockIdx.x * TM + wm * MF * 16 + m * 16 + kg * 4 + r;
                const long idx = cbase + (long)rowt * p.ldc + colt;
                float v = acc[m][n][r] + bv;
                if constexpr (EPI == 0) {
                    p.C[idx] = v;
                } else if constexpr (EPI == 1) {
                    p.C[idx] = v + p.resid[idx];
                } else {
                    float g = 1.f / (1.f + expf(-v));
                    p.C[idx] = p.resid[idx] + g * p.fus[idx];
                }
            }
        }
}

// ================= batched MoE GEMM: TK=64, gload_lds, 2D XCD partition =================
struct MoeP {
    const u16* A; int lda;
    const u16* Bw; long bStrideE; int ldb;
    u16* HHo;
    float* M1; float* M2;
    int ldc;
    const float* biasE; long biasStride;
    const float* combine;
    const int* cnt;
    const int* pfx;
    const int* tlist;
    int K;
};

// EPI: 3 = gelu -> bf16 into HHo; 4 = combine-weighted exactly-once write into M1/M2
template<int EPI, int NF>
__global__ __launch_bounds__(256)
void gemm_moe(MoeP p)
{
    constexpr int TN = 2 * NF * 16;
    constexpr int TK = 64;
    constexpr int BCH = TN / 32;
    const int ex = blockIdx.z;
    const int count = p.cnt[ex];
    // ---- 2D XCD partition: XCD c = orig%8 owns x-half (c&1) x y-quarter (c>>1);
    //      within region, by varies fastest (B slab stays L2-hot). Bijective:
    //      local in [0, hx*hy) with hx = gx/2, hy = gy/4, hx*hy = nwg/8.
    const int orig = blockIdx.x + gridDim.x * blockIdx.y;
    const int c8 = orig & 7;
    const int local = orig >> 3;
    const int hx = gridDim.x >> 1;
    const int hy = gridDim.y >> 2;
    const int bx = (c8 & 1) * hx + (local / hy);
    const int by = (c8 >> 1) * hy + (local % hy);
    if ((int)(bx * 128) >= count) return;
    const int base = p.pfx[ex];
    __shared__ __align__(16) u16 lA[128 * TK];
    __shared__ __align__(16) u16 lB[TN * TK];
    const int tid = threadIdx.x;
    const u16* Ab = p.A + (long)(base + bx * 128) * p.lda;
    const u16* Bb = p.Bw + (long)ex * p.bStrideE + (long)by * TN * p.ldb;
    const int lane = tid & 63;
    const int wv = tid >> 6;
    const int wm = wv >> 1;
    const int wn = wv & 1;
    const int kg = lane >> 4;
    const int l16 = lane & 15;
    f32x4 acc[4][NF];
#pragma unroll
    for (int m = 0; m < 4; ++m)
#pragma unroll
        for (int n = 0; n < NF; ++n)
            acc[m][n] = (f32x4){0.f, 0.f, 0.f, 0.f};

    const u16* pa[4]; u16* la[4];
#pragma unroll
    for (int i = 0; i < 4; ++i) {
        int e = i * 256 + tid;
        int r = e >> 3;
        int jg = (e & 7) ^ (r & 7);
        pa[i] = &Ab[(long)r * p.lda + jg * 8];
        la[i] = &lA[e * 8];
    }
    const u16* pb[BCH]; u16* lb[BCH];
#pragma unroll
    for (int i = 0; i < BCH; ++i) {
        int e = i * 256 + tid;
        int r = e >> 3;
        int jg = (e & 7) ^ (r & 7);
        pb[i] = &Bb[(long)r * p.ldb + jg * 8];
        lb[i] = &lB[e * 8];
    }

    for (int k0 = 0; k0 < p.K; k0 += TK) {
#pragma unroll
        for (int i = 0; i < 4; ++i) gld16(pa[i] + k0, la[i]);
#pragma unroll
        for (int i = 0; i < BCH; ++i) gld16(pb[i] + k0, lb[i]);
        __syncthreads();
#pragma unroll
        for (int ks = 0; ks < 2; ++ks) {
            short8 af[4], bfr[NF];
#pragma unroll
            for (int m = 0; m < 4; ++m) {
                int row = wm * 64 + m * 16 + l16;
                int jj = (ks * 4 + kg) ^ (row & 7);
                af[m] = *(const short8*)&lA[row * TK + jj * 8];
            }
#pragma unroll
            for (int n = 0; n < NF; ++n) {
                int row = wn * NF * 16 + n * 16 + l16;
                int jj = (ks * 4 + kg) ^ (row & 7);
                bfr[n] = *(const short8*)&lB[row * TK + jj * 8];
            }
#pragma unroll
            for (int m = 0; m < 4; ++m)
#pragma unroll
                for (int n = 0; n < NF; ++n)
                    acc[m][n] = __builtin_amdgcn_mfma_f32_16x16x32_bf16(af[m], bfr[n], acc[m][n], 0, 0, 0);
        }
        __syncthreads();
    }
    const float* bias = p.biasE + (long)ex * p.biasStride;
#pragma unroll
    for (int m = 0; m < 4; ++m)
#pragma unroll
        for (int n = 0; n < NF; ++n) {
            const int colt = by * TN + wn * NF * 16 + n * 16 + l16;
            const float bv = bias[colt];
#pragma unroll
            for (int r = 0; r < 4; ++r) {
                const int rowt = bx * 128 + wm * 64 + m * 16 + kg * 4 + r;
                if (rowt >= count) continue;
                float v = acc[m][n][r] + bv;
                if constexpr (EPI == 3) {
                    p.HHo[(long)(base + rowt) * p.ldc + colt] = f2b(gelu_f(v));
                } else {
                    const int entry = p.tlist[ex * 8192 + rowt];
                    const int tok = entry & 0xFFFF;
                    const int k = entry >> 16;
                    const float w = p.combine[(long)tok * 8 + ex];
                    float* dst = k ? p.M2 : p.M1;
                    dst[(long)tok * p.ldc + colt] = w * v;
                }
            }
        }
}

// ================= two-pass LayerNorm over 1024 (f32 in, f32 out) =================
// MODE 0: plain. MODE 2: in + add1 + add2.
template<int MODE>
__global__ __launch_bounds__(256)
void ln2p(const float* in, const float* add1, const float* add2,
          const float* w, const float* b, float* outf)
{
    const long row = blockIdx.x;
    const int t = threadIdx.x;
    const int c0 = t * 4;
    f32x4 v = *(const f32x4*)&in[row * 1024 + c0];
    if constexpr (MODE == 2) {
        f32x4 a1 = *(const f32x4*)&add1[row * 1024 + c0];
        f32x4 a2 = *(const f32x4*)&add2[row * 1024 + c0];
#pragma unroll
        for (int j = 0; j < 4; ++j) v[j] += a1[j] + a2[j];
    }
    __shared__ float r1[4], r2[4];
    const int lane = t & 63, wv = t >> 6;
    float s1 = v[0] + v[1] + v[2] + v[3];
    for (int o = 32; o; o >>= 1) s1 += __shfl_xor(s1, o);
    if (lane == 0) r1[wv] = s1;
    __syncthreads();
    const float mean = (r1[0] + r1[1] + r1[2] + r1[3]) * (1.f / 1024.f);
    f32x4 d;
#pragma unroll
    for (int j = 0; j < 4; ++j) d[j] = v[j] - mean;
    float s2 = d[0] * d[0] + d[1] * d[1] + d[2] * d[2] + d[3] * d[3];
    for (int o = 32; o; o >>= 1) s2 += __shfl_xor(s2, o);
    if (lane == 0) r2[wv] = s2;
    __syncthreads();
    const float var = (r2[0] + r2[1] + r2[2] + r2[3]) * (1.f / 1024.f);
    const float rstd = 1.f / sqrtf(var + 1e-5f);
    f32x4 o4;
#pragma unroll
    for (int j = 0; j < 4; ++j) o4[j] = d[j] * rstd * w[c0 + j] + b[c0 + j];
    *(f32x4*)&outf[row * 1024 + c0] = o4;
}

// per-row mean/rstd of f32 [rows,1024] -> st[row*2]; also zeroes cnt[0..7] (block 0)
__global__ __launch_bounds__(256)
void rowstats(const float* in, float* st, int* cnt)
{
    if (blockIdx.x == 0 && threadIdx.x < 8) cnt[threadIdx.x] = 0;
    const long row = blockIdx.x;
    const int t = threadIdx.x;
    const int c0 = t * 4;
    f32x4 v = *(const f32x4*)&in[row * 1024 + c0];
    __shared__ float r1[4], r2[4];
    const int lane = t & 63, wv = t >> 6;
    float s1 = v[0] + v[1] + v[2] + v[3];
    for (int o = 32; o; o >>= 1) s1 += __shfl_xor(s1, o);
    if (lane == 0) r1[wv] = s1;
    __syncthreads();
    const float mean = (r1[0] + r1[1] + r1[2] + r1[3]) * (1.f / 1024.f);
    float s2 = 0.f;
#pragma unroll
    for (int j = 0; j < 4; ++j) { float d = v[j] - mean; s2 += d * d; }
    for (int o = 32; o; o >>= 1) s2 += __shfl_xor(s2, o);
    if (lane == 0) r2[wv] = s2;
    __syncthreads();
    if (t == 0) {
        const float var = (r2[0] + r2[1] + r2[2] + r2[3]) * (1.f / 1024.f);
        st[row * 2] = mean;
        st[row * 2 + 1] = 1.f / sqrtf(var + 1e-5f);
    }
}

// ================= row softmax (f32 in-place), scale pre-max =================
__global__ __launch_bounds__(256)
void softmax_f32(float* sm, int C, float scale)
{
    const long row = blockIdx.x;
    float* p = sm + row * (long)C;
    const int t = threadIdx.x;
    const int idx = t * 4;
    const bool act = idx < C;
    f32x4 v = (f32x4){-1e30f, -1e30f, -1e30f, -1e30f};
    if (act) {
        v = *(const f32x4*)&p[idx];
#pragma unroll
        for (int j = 0; j < 4; ++j) v[j] *= scale;
    }
    float mx = fmaxf(fmaxf(v[0], v[1]), fmaxf(v[2], v[3]));
    for (int o = 32; o; o >>= 1) mx = fmaxf(mx, __shfl_xor(mx, o));
    __shared__ float red[4], red2[4];
    const int lane = t & 63, wv = t >> 6;
    if (lane == 0) red[wv] = mx;
    __syncthreads();
    mx = fmaxf(fmaxf(red[0], red[1]), fmaxf(red[2], red[3]));
    float e[4], s = 0.f;
    if (act) {
#pragma unroll
        for (int j = 0; j < 4; ++j) { e[j] = expf(v[j] - mx); s += e[j]; }
    }
    for (int o = 32; o; o >>= 1) s += __shfl_xor(s, o);
    if (lane == 0) red2[wv] = s;
    __syncthreads();
    s = red2[0] + red2[1] + red2[2] + red2[3];
    if (act) {
        f32x4 o4;
#pragma unroll
        for (int j = 0; j < 4; ++j) o4[j] = e[j] / s;
        *(f32x4*)&p[idx] = o4;
    }
}

// ================= transpose V (f32) =================
__global__ __launch_bounds__(256)
void transpose64f(const float* src, int sld, long sSo, long sSi, int sDiv, float* dst, int Skv)
{
    const int z = blockIdx.y;
    const float* Sp = src + (long)(z / sDiv) * sSo + (long)(z % sDiv) * sSi;
    float* Dp = dst + (long)z * 64 * Skv;
    const int j0 = blockIdx.x * 64;
    __shared__ float tl[64][68];
    const int tid = threadIdx.x;
#pragma unroll
    for (int it = 0; it < 4; ++it) {
        int e = (it * 256 + tid) * 4;
        int r = e >> 6, c = e & 63;
        f32x4 d = *(const f32x4*)&Sp[(long)(j0 + r) * sld + c];
        *(f32x4*)&tl[r][c] = d;
    }
    __syncthreads();
    const int d0 = tid >> 2;
    const int jc = (tid & 3) * 16;
    float tmp[16];
#pragma unroll
    for (int i = 0; i < 16; ++i) tmp[i] = tl[jc + i][d0];
#pragma unroll
    for (int i = 0; i < 16; ++i) Dp[(long)d0 * Skv + j0 + jc + i] = tmp[i];
}

// ================= PV K-split partial reduce: xn += sum of 4 partials =================
__global__ __launch_bounds__(256)
void pvred(const float* pp, float* xn, int g)
{
    const long i = (long)blockIdx.x * 256 + threadIdx.x;   // 0..524287 f32x4 groups
    const long e = i * 4;
    const int z = (int)(e >> 16);
    const int rem = (int)(e & 65535);
    const int row = rem >> 6;
    const int col = rem & 63;
    f32x4 a = *(const f32x4*)&pp[e];
    f32x4 b = *(const f32x4*)&pp[2097152 + e];
    f32x4 c = *(const f32x4*)&pp[2 * 2097152 + e];
    f32x4 d = *(const f32x4*)&pp[3 * 2097152 + e];
    f32x4 s;
#pragma unroll
    for (int j = 0; j < 4; ++j) s[j] = (a[j] + b[j]) + (c[j] + d[j]);
    float* dst = xn + (long)g * 2097152 + (long)(z >> 4) * 1048576
               + (long)row * 1024 + (z & 15) * 64 + col;
    *(f32x4*)dst = s;
}

// ================= router: f64 logits, top2 -> combine + tagged per-expert lists =================
__global__ __launch_bounds__(256)
void router_k(const float* xn2, const float* rw, const float* rb, float* cmb,
              int* cnt, int* tlist)
{
    const int tok = blockIdx.x * 4 + (threadIdx.x >> 6);
    const int lane = threadIdx.x & 63;
    const float* xp = xn2 + (long)tok * 1024 + lane * 16;
    float xv[16];
#pragma unroll
    for (int j = 0; j < 16; ++j) xv[j] = xp[j];
    double acc[8];
#pragma unroll
    for (int e = 0; e < 8; ++e) {
        const float* wp = rw + e * 1024 + lane * 16;
        double s = 0.0;
#pragma unroll
        for (int j = 0; j < 16; ++j) s += (double)xv[j] * (double)wp[j];
        acc[e] = s;
    }
    for (int o = 32; o; o >>= 1) {
#pragma unroll
        for (int e = 0; e < 8; ++e) acc[e] += __shfl_xor(acc[e], o);
    }
    if (lane == 0) {
        double l[8];
#pragma unroll
        for (int e = 0; e < 8; ++e) l[e] = acc[e] + (double)rb[e];
        int i1 = 0;
#pragma unroll
        for (int e = 1; e < 8; ++e) if (l[e] > l[i1]) i1 = e;
        int i2 = (i1 == 0) ? 1 : 0;
#pragma unroll
        for (int e = 0; e < 8; ++e) if (e != i1 && l[e] > l[i2]) i2 = e;
        double w1 = 1.0 / (1.0 + exp(l[i2] - l[i1]));
        double w2 = 1.0 - w1;
        float c8[8] = {0, 0, 0, 0, 0, 0, 0, 0};
        c8[i1] = (float)w1;
        c8[i2] = (float)w2;
        float* cp = cmb + (long)tok * 8;
#pragma unroll
        for (int e = 0; e < 8; ++e) cp[e] = c8[e];
        int s1 = atomicAdd(&cnt[i1], 1);
        tlist[i1 * 8192 + s1] = tok;              // k=0
        int s2 = atomicAdd(&cnt[i2], 1);
        tlist[i2 * 8192 + s2] = tok | 65536;      // k=1
    }
}

// exclusive prefix over 8 counts
__global__ void prefix8(const int* cnt, int* pfx)
{
    if (threadIdx.x == 0) {
        int s = 0;
#pragma unroll
        for (int e = 0; e < 8; ++e) { pfx[e] = s; s += cnt[e]; }
    }
}

// gather all experts: XE[pfx[e]+slot] = bf16((xn2[tok]-m)*rstd*w_e + b_e)
__global__ __launch_bounds__(256)
void gather_all(const float* xn2, const float* st, const int* cnt, const int* pfx,
                const int* tlist, const float* lnw, const float* lnb, u16* xe)
{
    const int e = blockIdx.y;
    const int slot = blockIdx.x;
    if (slot >= cnt[e]) return;
    const int tok = tlist[e * 8192 + slot] & 0xFFFF;
    const int c0 = threadIdx.x * 4;
    f32x4 v = *(const f32x4*)&xn2[(long)tok * 1024 + c0];
    const float m = st[tok * 2], r = st[tok * 2 + 1];
    const float* w = lnw + (long)e * 1024;
    const float* b = lnb + (long)e * 1024;
    short4v o4;
#pragma unroll
    for (int j = 0; j < 4; ++j) o4[j] = (short)f2b((v[j] - m) * r * w[c0 + j] + b[c0 + j]);
    *(short4v*)&xe[(long)(pfx[e] + slot) * 1024 + c0] = o4;
}

// ================= grid-stride f32 -> bf16 weight conversion =================
__global__ __launch_bounds__(256)
void cvtw(const float* in, u16* out, long n4)
{
    const long stride = (long)gridDim.x * 256;
    for (long i = (long)blockIdx.x * 256 + threadIdx.x; i < n4; i += stride) {
        f32x4 v = *(const f32x4*)&in[i * 4];
        short4v o;
#pragma unroll
        for (int j = 0; j < 4; ++j) o[j] = (short)f2b(v[j]);
        *(short4v*)&out[i * 4] = o;
    }
}

extern "C" void kernel_launch(void* const* d_in, const int* in_sizes, int n_in,
                              void* d_out, int out_size, void* d_ws, size_t ws_size,
                              hipStream_t stream)
{
    (void)in_sizes; (void)n_in; (void)out_size;
    const float* x          = (const float*)d_in[0];
    const float* modal      = (const float*)d_in[1];
    const float* attn_in_w  = (const float*)d_in[2];
    const float* attn_in_b  = (const float*)d_in[3];
    const float* attn_out_w = (const float*)d_in[4];
    const float* attn_out_b = (const float*)d_in[5];
    const float* xattn_in_w = (const float*)d_in[6];
    const float* xattn_in_b = (const float*)d_in[7];
    const float* xattn_out_w= (const float*)d_in[8];
    const float* xattn_out_b= (const float*)d_in[9];
    const float* norm1_w = (const float*)d_in[10];
    const float* norm1_b = (const float*)d_in[11];
    const float* norm2_w = (const float*)d_in[12];
    const float* norm2_b = (const float*)d_in[13];
    const float* norm3_w = (const float*)d_in[14];
    const float* norm3_b = (const float*)d_in[15];
    const float* xnorm_w = (const float*)d_in[16];
    const float* xnorm_b = (const float*)d_in[17];
    const float* router_w = (const float*)d_in[18];
    const float* router_b = (const float*)d_in[19];
    const float* gate_w = (const float*)d_in[20];
    const float* gate_b = (const float*)d_in[21];
    const float* exp_ln_w = (const float*)d_in[22];
    const float* exp_ln_b = (const float*)d_in[23];
    const float* exp_fc1_w = (const float*)d_in[24];
    const float* exp_fc1_b = (const float*)d_in[25];
    const float* exp_fc2_w = (const float*)d_in[26];
    const float* exp_fc2_b = (const float*)d_in[27];

    char* wsb = (char*)d_ws;
    size_t off = 0;
    auto AL = [&](size_t bytes) { size_t r = off; off += (bytes + 255) & ~(size_t)255; return r; };
    float* XN  = (float*)(wsb + AL(33554432));   // 8192x1024 f32; MoE phase: bf16 weight store (with H)
    float* H   = (float*)(wsb + AL(33554432));
    float* H2  = (float*)(wsb + AL(33554432));   // attn phase: self-scores region (H2..MOE = 128MiB)
    float* XN2 = (float*)(wsb + AL(33554432));
    float* FUS = (float*)(wsb + AL(33554432));
    float* MOE = (float*)(wsb + AL(33554432));
    float* XKV = (float*)(wsb + AL(8388608));    // 1024x2048 f32
    float* CMB = (float*)(wsb + AL(262144));     // 8192x8 f32
    float* ST  = (float*)(wsb + AL(65536));      // 8192x2 f32
    int*   CNT = (int*)(wsb + AL(256));          // 8 ints
    int*   PFX = (int*)(wsb + AL(256));          // 8 ints
    int*   TLS = (int*)(wsb + AL(262144));       // 8x8192 ints (tok | k<<16)
    char*  RA  = wsb + AL(100663296);            // 96MB  } contiguous 192MB region
    char*  RB  = wsb + AL(100663296);            // 96MB  }
    if (off > ws_size) return;                   // loud failure

    float* QKV = (float*)RA;                     // [8192,3072]
    float* XQ  = (float*)RA;                     // [8192,1024]
    float* XO  = (float*)(RA + 33554432);        // [8192,1024]
    float* SCf = (float*)RB;                     // cross scores (64MB)
    float* PP  = (float*)RB;                     // PV partials [4][32][1024][64] f32 = 32MB (self-attn phase)
    float* VTf = (float*)(RB + 67108864);        // V^T (32MB)
    float* SC2 = H2;                             // self scores: 32bh x 1024 x 1024 f32 (H2..MOE dead)
    u16*   HH  = (u16*)RA;                       // MoE phase
    u16*   XE  = (u16*)(RA + 135266304);
    u16*   WB  = (u16*)XN;                       // 64MB bf16 weight buffer (MoE phase, XN∪H dead)
    float* out = (float*)d_out;

    // 1) ln1 = LN(x, norm1) -> XN
    ln2p<0><<<8192, 256, 0, stream>>>(x, nullptr, nullptr, norm1_w, norm1_b, XN);

    // 2) qkv = ln1 @ attn_in_w^T + b -> QKV
    {
        EGemmP p{XN, 1024, 0, 0, 1, attn_in_w, 1024, 0, 0, 1,
                 QKV, 3072, 0, 0, 1, attn_in_b, nullptr, nullptr, 1024};
        gemm_emu<0, 2, 2, 4, 2><<<dim3(64, 48, 1), 256, 0, stream>>>(p);
    }
    // 2b) self V -> VTf[bh][64][1024]
    transpose64f<<<dim3(16, 128), 256, 0, stream>>>(QKV + 2048, 3072, (long)1024 * 3072, 64, 16, VTf, 1024);

    // 3) self-attention in 4 chunks of 32 bh; scores in SC2; PV K-split x4 into PP then reduce
    for (int g = 0; g < 4; ++g) {
        EGemmP s{QKV + (long)g * 2 * 1024 * 3072, 3072, (long)1024 * 3072, 64, 16,
                 QKV + 1024 + (long)g * 2 * 1024 * 3072, 3072, (long)1024 * 3072, 64, 16,
                 SC2, 1024, 0, (long)1024 * 1024, 1 << 20, nullptr, nullptr, nullptr, 64};
        gemm_emu<0, 2, 2, 4, 2><<<dim3(8, 16, 32), 256, 0, stream>>>(s);

        softmax_f32<<<32 * 1024, 256, 0, stream>>>(SC2, 1024, 0.125f);

        EGemmP v{SC2, 1024, 256, (long)1024 * 1024, 32,
                 VTf + (long)g * 32 * 64 * 1024, 1024, 256, (long)64 * 1024, 32,
                 PP, 64, 2097152, 65536, 32, nullptr, nullptr, nullptr, 256};
        gemm_emu<0, 2, 2, 2, 2><<<dim3(16, 1, 128), 256, 0, stream>>>(v);

        pvred<<<2048, 256, 0, stream>>>(PP, XN, g);
    }

    // 4) h = x + o @ attn_out_w^T + b -> H
    {
        EGemmP p{XN, 1024, 0, 0, 1, attn_out_w, 1024, 0, 0, 1,
                 H, 1024, 0, 0, 1, attn_out_b, x, nullptr, 1024};
        gemm_emu<1, 2, 2, 4, 2><<<dim3(64, 16, 1), 256, 0, stream>>>(p);
    }
    // 5) xn = LN(h, xnorm) -> XN
    ln2p<0><<<8192, 256, 0, stream>>>(H, nullptr, nullptr, xnorm_w, xnorm_b, XN);

    // 6) xq = xn @ xattn_in_w[0:E]^T + b -> XQ
    {
        EGemmP p{XN, 1024, 0, 0, 1, xattn_in_w, 1024, 0, 0, 1,
                 XQ, 1024, 0, 0, 1, xattn_in_b, nullptr, nullptr, 1024};
        gemm_emu<0, 2, 2, 4, 2><<<dim3(64, 16, 1), 256, 0, stream>>>(p);
    }
    // 7) xkv = modal @ xattn_in_w[E:3E]^T + b -> XKV
    {
        EGemmP p{modal, 1024, 0, 0, 1, xattn_in_w + (size_t)1024 * 1024, 1024, 0, 0, 1,
                 XKV, 2048, 0, 0, 1, xattn_in_b + 1024, nullptr, nullptr, 1024};
        gemm_emu<0, 2, 2, 4, 2><<<dim3(8, 32, 1), 256, 0, stream>>>(p);
    }
    // 7b) cross V -> VTf[bh][64][128]
    transpose64f<<<dim3(2, 128), 256, 0, stream>>>(XKV + 1024, 2048, (long)128 * 2048, 64, 16, VTf, 128);

    // 8) cross scores -> SCf
    {
        EGemmP s{XQ, 1024, (long)1024 * 1024, 64, 16,
                 XKV, 2048, (long)128 * 2048, 64, 16,
                 SCf, 128, 0, (long)1024 * 128, 1 << 20, nullptr, nullptr, nullptr, 64};
        gemm_emu<0, 2, 2, 4, 2><<<dim3(8, 2, 128), 256, 0, stream>>>(s);
    }
    softmax_f32<<<128 * 1024, 256, 0, stream>>>(SCf, 128, 0.125f);
    // 9) xo = P @ V -> XO
    {
        EGemmP v{SCf, 128, 0, (long)1024 * 128, 1 << 20,
                 VTf, 128, 0, (long)64 * 128, 1 << 20,
                 XO, 1024, (long)1024 * 1024, 64, 16, nullptr, nullptr, nullptr, 128};
        gemm_emu<0, 2, 2, 4, 2><<<dim3(8, 1, 128), 256, 0, stream>>>(v);
    }
    // 10) fusion = xo @ xattn_out_w^T + b -> FUS
    {
        EGemmP p{XO, 1024, 0, 0, 1, xattn_out_w, 1024, 0, 0, 1,
                 FUS, 1024, 0, 0, 1, xattn_out_b, nullptr, nullptr, 1024};
        gemm_emu<0, 2, 2, 4, 2><<<dim3(64, 16, 1), 256, 0, stream>>>(p);
    }
    // 11) h2 = h + sigmoid(xn @ gate_w^T + gate_b) * fusion -> H2
    {
        EGemmP p{XN, 1024, 0, 0, 1, gate_w, 1024, 0, 0, 1,
                 H2, 1024, 0, 0, 1, gate_b, H, FUS, 1024};
        gemm_emu<2, 2, 2, 4, 2><<<dim3(64, 16, 1), 256, 0, stream>>>(p);
    }
    // 12) xn2 = LN(h2, norm2); rowstats (+cnt zero); router; prefix
    ln2p<0><<<8192, 256, 0, stream>>>(H2, nullptr, nullptr, norm2_w, norm2_b, XN2);
    rowstats<<<8192, 256, 0, stream>>>(XN2, ST, CNT);
    router_k<<<2048, 256, 0, stream>>>(XN2, router_w, router_b, CMB, CNT, TLS);
    prefix8<<<1, 64, 0, stream>>>(CNT, PFX);

    // 13) sparse experts: gather_all -> cvt fc1 wts -> fc1 -> cvt fc2 wts -> fc2
    gather_all<<<dim3(8192, 8), 256, 0, stream>>>(XN2, ST, CNT, PFX, TLS, exp_ln_w, exp_ln_b, XE);
    cvtw<<<2048, 256, 0, stream>>>(exp_fc1_w, WB, 8388608);   // 8x4096x1024
    {
        MoeP p1{XE, 1024, WB, (long)4096 * 1024, 1024,
                HH, nullptr, nullptr, 4096,
                exp_fc1_b, 4096, nullptr, CNT, PFX, TLS, 1024};
        gemm_moe<3, 4><<<dim3(64, 32, 8), 256, 0, stream>>>(p1);
    }
    cvtw<<<2048, 256, 0, stream>>>(exp_fc2_w, WB, 8388608);   // 8x1024x4096
    {
        MoeP p2{HH, 4096, WB, (long)1024 * 4096, 4096,
                nullptr, MOE, FUS, 1024,
                exp_fc2_b, 1024, CMB, CNT, PFX, TLS, 4096};
        gemm_moe<4, 2><<<dim3(64, 16, 8), 256, 0, stream>>>(p2);
    }

    // 14) out = LN(h2 + moe1 + moe2, norm3) -> f32 d_out
    ln2p<2><<<8192, 256, 0, stream>>>(H2, MOE, FUS, norm3_w, norm3_b, out);
}

// Round 18
// 2592.781 us; speedup vs baseline: 1.1084x; 1.1084x over previous
//
#include <hip/hip_runtime.h>
#include <cstdint>
#include <cstddef>
#include <math.h>

typedef unsigned short u16;
typedef __attribute__((ext_vector_type(4))) float f32x4;
typedef __attribute__((ext_vector_type(8))) short short8;
typedef __attribute__((ext_vector_type(4))) short short4v;

__device__ __forceinline__ float b2f(u16 u) {
    union { unsigned int i; float f; } v; v.i = ((unsigned int)u) << 16; return v.f;
}
__device__ __forceinline__ u16 f2b(float f) {
    union { float f; unsigned int i; } v; v.f = f;
    unsigned int i = v.i;
    return (u16)((i + 0x7FFFu + ((i >> 16) & 1u)) >> 16);
}
// exact truncation-based 3-way split: a = h + m + l' with |err| <= 2^-24|a|
__device__ __forceinline__ void split3t(float a, short& h, short& m, short& l) {
    union { float f; unsigned int u; } va, vh, v1, vm, v2;
    va.f = a;
    vh.u = va.u & 0xFFFF0000u;
    float r1 = a - vh.f;                 // exact
    v1.f = r1;
    vm.u = v1.u & 0xFFFF0000u;
    float r2 = r1 - vm.f;                // exact
    v2.f = r2;
    h = (short)(vh.u >> 16);
    m = (short)(vm.u >> 16);
    l = (short)(v2.u >> 16);
}
__device__ __forceinline__ float gelu_f(float x) {
    float x3 = x * x * x;
    float y = 0.7978845608028654f * (x + 0.044715f * x3);
    float ya = fminf(fabsf(y), 15.f);
    float e = expf(-2.f * ya);
    float t = (1.f - e) / (1.f + e);
    t = copysignf(t, y);
    return 0.5f * x * (1.f + t);
}
// async global->LDS, 16 bytes per lane; LDS dest must be linear (wave base + lane*16)
__device__ __forceinline__ void gld16(const u16* g, u16* l)
{
    __builtin_amdgcn_global_load_lds(
        (const __attribute__((address_space(1))) void*)(g),
        (__attribute__((address_space(3))) void*)(l),
        16, 0, 0);
}

// ================= f32-faithful GEMM via 6-term bf16x3 MFMA emulation =================
struct EGemmP {
    const float* A; int lda; long aSo, aSi; int aDiv;
    const float* B; int ldb; long bSo, bSi; int bDiv;
    float* C; int ldc; long cSo, cSi; int cDiv;
    const float* bias;
    const float* resid;   // EPI 1,2
    const float* fus;     // EPI 2
    int K;
};

// EPI: 0 = store f32; 1 = v + resid; 2 = resid + sigmoid(v)*fus
template<int EPI, int WM, int WN, int MF, int NF>
__global__ __launch_bounds__(256)
void gemm_emu(EGemmP p)
{
    constexpr int TM = WM * MF * 16;
    constexpr int TN = WN * NF * 16;
    constexpr int TK = 32;
    __shared__ u16 Ah[TM * TK], Am[TM * TK], Al[TM * TK];
    __shared__ u16 Bh[TN * TK], Bm[TN * TK], Bl[TN * TK];
    const int tid = threadIdx.x;
    const int z = blockIdx.z;
    const float* Ab = p.A + (long)(z / p.aDiv) * p.aSo + (long)(z % p.aDiv) * p.aSi
                      + (long)blockIdx.x * TM * p.lda;
    const float* Bb = p.B + (long)(z / p.bDiv) * p.bSo + (long)(z % p.bDiv) * p.bSi
                      + (long)blockIdx.y * TN * p.ldb;
    const int lane = tid & 63;
    const int wv = tid >> 6;
    const int wm = wv / WN;
    const int wn = wv % WN;
    const int kg = lane >> 4;
    const int l16 = lane & 15;
    f32x4 acc[MF][NF];
#pragma unroll
    for (int m = 0; m < MF; ++m)
#pragma unroll
        for (int n = 0; n < NF; ++n)
            acc[m][n] = (f32x4){0.f, 0.f, 0.f, 0.f};

    for (int k0 = 0; k0 < p.K; k0 += TK) {
#pragma unroll
        for (int i = 0; i < (TM * TK) / 1024; ++i) {
            int e = i * 256 + tid;
            int r = e >> 3;
            int c = (e & 7) * 4;
            f32x4 a = *(const f32x4*)&Ab[(long)r * p.lda + k0 + c];
            short4v h, m, l;
#pragma unroll
            for (int j = 0; j < 4; ++j) {
                short th, tm2, tl2;
                split3t(a[j], th, tm2, tl2);
                h[j] = th; m[j] = tm2; l[j] = tl2;
            }
            *(short4v*)&Ah[r * TK + c] = h;
            *(short4v*)&Am[r * TK + c] = m;
            *(short4v*)&Al[r * TK + c] = l;
        }
#pragma unroll
        for (int i = 0; i < (TN * TK) / 1024; ++i) {
            int e = i * 256 + tid;
            int r = e >> 3;
            int c = (e & 7) * 4;
            f32x4 a = *(const f32x4*)&Bb[(long)r * p.ldb + k0 + c];
            short4v h, m, l;
#pragma unroll
            for (int j = 0; j < 4; ++j) {
                short th, tm2, tl2;
                split3t(a[j], th, tm2, tl2);
                h[j] = th; m[j] = tm2; l[j] = tl2;
            }
            *(short4v*)&Bh[r * TK + c] = h;
            *(short4v*)&Bm[r * TK + c] = m;
            *(short4v*)&Bl[r * TK + c] = l;
        }
        __syncthreads();
        short8 ah[MF], am[MF], al[MF], bh[NF], bm[NF], bl[NF];
#pragma unroll
        for (int m = 0; m < MF; ++m) {
            int ro = (wm * MF * 16 + m * 16 + l16) * TK + kg * 8;
            ah[m] = *(const short8*)&Ah[ro];
            am[m] = *(const short8*)&Am[ro];
            al[m] = *(const short8*)&Al[ro];
        }
#pragma unroll
        for (int n = 0; n < NF; ++n) {
            int ro = (wn * NF * 16 + n * 16 + l16) * TK + kg * 8;
            bh[n] = *(const short8*)&Bh[ro];
            bm[n] = *(const short8*)&Bm[ro];
            bl[n] = *(const short8*)&Bl[ro];
        }
#pragma unroll
        for (int m = 0; m < MF; ++m)
#pragma unroll
            for (int n = 0; n < NF; ++n) {
                f32x4 a = acc[m][n];
                a = __builtin_amdgcn_mfma_f32_16x16x32_bf16(al[m], bh[n], a, 0, 0, 0);
                a = __builtin_amdgcn_mfma_f32_16x16x32_bf16(ah[m], bl[n], a, 0, 0, 0);
                a = __builtin_amdgcn_mfma_f32_16x16x32_bf16(am[m], bm[n], a, 0, 0, 0);
                a = __builtin_amdgcn_mfma_f32_16x16x32_bf16(am[m], bh[n], a, 0, 0, 0);
                a = __builtin_amdgcn_mfma_f32_16x16x32_bf16(ah[m], bm[n], a, 0, 0, 0);
                a = __builtin_amdgcn_mfma_f32_16x16x32_bf16(ah[m], bh[n], a, 0, 0, 0);
                acc[m][n] = a;
            }
        __syncthreads();
    }
    const long cbase = (long)(z / p.cDiv) * p.cSo + (long)(z % p.cDiv) * p.cSi;
#pragma unroll
    for (int m = 0; m < MF; ++m)
#pragma unroll
        for (int n = 0; n < NF; ++n) {
            const int colt = blockIdx.y * TN + wn * NF * 16 + n * 16 + l16;
            float bv = p.bias ? p.bias[colt] : 0.f;
#pragma unroll
            for (int r = 0; r < 4; ++r) {
                const int rowt = blockIdx.x * TM + wm * MF * 16 + m * 16 + kg * 4 + r;
                const long idx = cbase + (long)rowt * p.ldc + colt;
                float v = acc[m][n][r] + bv;
                if constexpr (EPI == 0) {
                    p.C[idx] = v;
                } else if constexpr (EPI == 1) {
                    p.C[idx] = v + p.resid[idx];
                } else {
                    float g = 1.f / (1.f + expf(-v));
                    p.C[idx] = p.resid[idx] + g * p.fus[idx];
                }
            }
        }
}

// ================= batched MoE GEMM: r15 config (TK=64 + XCD-chunked swizzle) =================
struct MoeP {
    const u16* A; int lda;
    const u16* Bw; long bStrideE; int ldb;
    u16* HHo;
    float* M1; float* M2;
    int ldc;
    const float* biasE; long biasStride;
    const float* combine;
    const int* cnt;
    const int* pfx;
    const int* tlist;
    int K;
};

// EPI: 3 = gelu -> bf16 into HHo; 4 = combine-weighted exactly-once write into M1/M2
template<int EPI, int NF>
__global__ __launch_bounds__(256)
void gemm_moe(MoeP p)
{
    constexpr int TN = 2 * NF * 16;
    constexpr int TK = 64;
    constexpr int BCH = TN / 32;
    const int ex = blockIdx.z;
    const int count = p.cnt[ex];
    const int nwg = gridDim.x * gridDim.y;
    const int orig = blockIdx.x + gridDim.x * blockIdx.y;
    const int wg = (orig & 7) * (nwg >> 3) + (orig >> 3);
    const int bx = wg % gridDim.x;
    const int by = wg / gridDim.x;
    if ((int)(bx * 128) >= count) return;
    const int base = p.pfx[ex];
    __shared__ __align__(16) u16 lA[128 * TK];
    __shared__ __align__(16) u16 lB[TN * TK];
    const int tid = threadIdx.x;
    const u16* Ab = p.A + (long)(base + bx * 128) * p.lda;
    const u16* Bb = p.Bw + (long)ex * p.bStrideE + (long)by * TN * p.ldb;
    const int lane = tid & 63;
    const int wv = tid >> 6;
    const int wm = wv >> 1;
    const int wn = wv & 1;
    const int kg = lane >> 4;
    const int l16 = lane & 15;
    f32x4 acc[4][NF];
#pragma unroll
    for (int m = 0; m < 4; ++m)
#pragma unroll
        for (int n = 0; n < NF; ++n)
            acc[m][n] = (f32x4){0.f, 0.f, 0.f, 0.f};

    const u16* pa[4]; u16* la[4];
#pragma unroll
    for (int i = 0; i < 4; ++i) {
        int e = i * 256 + tid;
        int r = e >> 3;
        int jg = (e & 7) ^ (r & 7);
        pa[i] = &Ab[(long)r * p.lda + jg * 8];
        la[i] = &lA[e * 8];
    }
    const u16* pb[BCH]; u16* lb[BCH];
#pragma unroll
    for (int i = 0; i < BCH; ++i) {
        int e = i * 256 + tid;
        int r = e >> 3;
        int jg = (e & 7) ^ (r & 7);
        pb[i] = &Bb[(long)r * p.ldb + jg * 8];
        lb[i] = &lB[e * 8];
    }

    for (int k0 = 0; k0 < p.K; k0 += TK) {
#pragma unroll
        for (int i = 0; i < 4; ++i) gld16(pa[i] + k0, la[i]);
#pragma unroll
        for (int i = 0; i < BCH; ++i) gld16(pb[i] + k0, lb[i]);
        __syncthreads();
#pragma unroll
        for (int ks = 0; ks < 2; ++ks) {
            short8 af[4], bfr[NF];
#pragma unroll
            for (int m = 0; m < 4; ++m) {
                int row = wm * 64 + m * 16 + l16;
                int jj = (ks * 4 + kg) ^ (row & 7);
                af[m] = *(const short8*)&lA[row * TK + jj * 8];
            }
#pragma unroll
            for (int n = 0; n < NF; ++n) {
                int row = wn * NF * 16 + n * 16 + l16;
                int jj = (ks * 4 + kg) ^ (row & 7);
                bfr[n] = *(const short8*)&lB[row * TK + jj * 8];
            }
#pragma unroll
            for (int m = 0; m < 4; ++m)
#pragma unroll
                for (int n = 0; n < NF; ++n)
                    acc[m][n] = __builtin_amdgcn_mfma_f32_16x16x32_bf16(af[m], bfr[n], acc[m][n], 0, 0, 0);
        }
        __syncthreads();
    }
    const float* bias = p.biasE + (long)ex * p.biasStride;
#pragma unroll
    for (int m = 0; m < 4; ++m)
#pragma unroll
        for (int n = 0; n < NF; ++n) {
            const int colt = by * TN + wn * NF * 16 + n * 16 + l16;
            const float bv = bias[colt];
#pragma unroll
            for (int r = 0; r < 4; ++r) {
                const int rowt = bx * 128 + wm * 64 + m * 16 + kg * 4 + r;
                if (rowt >= count) continue;
                float v = acc[m][n][r] + bv;
                if constexpr (EPI == 3) {
                    p.HHo[(long)(base + rowt) * p.ldc + colt] = f2b(gelu_f(v));
                } else {
                    const int entry = p.tlist[ex * 8192 + rowt];
                    const int tok = entry & 0xFFFF;
                    const int k = entry >> 16;
                    const float w = p.combine[(long)tok * 8 + ex];
                    float* dst = k ? p.M2 : p.M1;
                    dst[(long)tok * p.ldc + colt] = w * v;
                }
            }
        }
}

// ================= two-pass LayerNorm over 1024 (f32 in, f32 out) =================
// MODE 0: plain. MODE 2: in + add1 + add2.
template<int MODE>
__global__ __launch_bounds__(256)
void ln2p(const float* in, const float* add1, const float* add2,
          const float* w, const float* b, float* outf)
{
    const long row = blockIdx.x;
    const int t = threadIdx.x;
    const int c0 = t * 4;
    f32x4 v = *(const f32x4*)&in[row * 1024 + c0];
    if constexpr (MODE == 2) {
        f32x4 a1 = *(const f32x4*)&add1[row * 1024 + c0];
        f32x4 a2 = *(const f32x4*)&add2[row * 1024 + c0];
#pragma unroll
        for (int j = 0; j < 4; ++j) v[j] += a1[j] + a2[j];
    }
    __shared__ float r1[4], r2[4];
    const int lane = t & 63, wv = t >> 6;
    float s1 = v[0] + v[1] + v[2] + v[3];
    for (int o = 32; o; o >>= 1) s1 += __shfl_xor(s1, o);
    if (lane == 0) r1[wv] = s1;
    __syncthreads();
    const float mean = (r1[0] + r1[1] + r1[2] + r1[3]) * (1.f / 1024.f);
    f32x4 d;
#pragma unroll
    for (int j = 0; j < 4; ++j) d[j] = v[j] - mean;
    float s2 = d[0] * d[0] + d[1] * d[1] + d[2] * d[2] + d[3] * d[3];
    for (int o = 32; o; o >>= 1) s2 += __shfl_xor(s2, o);
    if (lane == 0) r2[wv] = s2;
    __syncthreads();
    const float var = (r2[0] + r2[1] + r2[2] + r2[3]) * (1.f / 1024.f);
    const float rstd = 1.f / sqrtf(var + 1e-5f);
    f32x4 o4;
#pragma unroll
    for (int j = 0; j < 4; ++j) o4[j] = d[j] * rstd * w[c0 + j] + b[c0 + j];
    *(f32x4*)&outf[row * 1024 + c0] = o4;
}

// per-row mean/rstd of f32 [rows,1024] -> st[row*2]; also zeroes cnt[0..7] (block 0)
__global__ __launch_bounds__(256)
void rowstats(const float* in, float* st, int* cnt)
{
    if (blockIdx.x == 0 && threadIdx.x < 8) cnt[threadIdx.x] = 0;
    const long row = blockIdx.x;
    const int t = threadIdx.x;
    const int c0 = t * 4;
    f32x4 v = *(const f32x4*)&in[row * 1024 + c0];
    __shared__ float r1[4], r2[4];
    const int lane = t & 63, wv = t >> 6;
    float s1 = v[0] + v[1] + v[2] + v[3];
    for (int o = 32; o; o >>= 1) s1 += __shfl_xor(s1, o);
    if (lane == 0) r1[wv] = s1;
    __syncthreads();
    const float mean = (r1[0] + r1[1] + r1[2] + r1[3]) * (1.f / 1024.f);
    float s2 = 0.f;
#pragma unroll
    for (int j = 0; j < 4; ++j) { float d = v[j] - mean; s2 += d * d; }
    for (int o = 32; o; o >>= 1) s2 += __shfl_xor(s2, o);
    if (lane == 0) r2[wv] = s2;
    __syncthreads();
    if (t == 0) {
        const float var = (r2[0] + r2[1] + r2[2] + r2[3]) * (1.f / 1024.f);
        st[row * 2] = mean;
        st[row * 2 + 1] = 1.f / sqrtf(var + 1e-5f);
    }
}

// ================= row softmax (f32 in-place), scale pre-max =================
__global__ __launch_bounds__(256)
void softmax_f32(float* sm, int C, float scale)
{
    const long row = blockIdx.x;
    float* p = sm + row * (long)C;
    const int t = threadIdx.x;
    const int idx = t * 4;
    const bool act = idx < C;
    f32x4 v = (f32x4){-1e30f, -1e30f, -1e30f, -1e30f};
    if (act) {
        v = *(const f32x4*)&p[idx];
#pragma unroll
        for (int j = 0; j < 4; ++j) v[j] *= scale;
    }
    float mx = fmaxf(fmaxf(v[0], v[1]), fmaxf(v[2], v[3]));
    for (int o = 32; o; o >>= 1) mx = fmaxf(mx, __shfl_xor(mx, o));
    __shared__ float red[4], red2[4];
    const int lane = t & 63, wv = t >> 6;
    if (lane == 0) red[wv] = mx;
    __syncthreads();
    mx = fmaxf(fmaxf(red[0], red[1]), fmaxf(red[2], red[3]));
    float e[4], s = 0.f;
    if (act) {
#pragma unroll
        for (int j = 0; j < 4; ++j) { e[j] = expf(v[j] - mx); s += e[j]; }
    }
    for (int o = 32; o; o >>= 1) s += __shfl_xor(s, o);
    if (lane == 0) red2[wv] = s;
    __syncthreads();
    s = red2[0] + red2[1] + red2[2] + red2[3];
    if (act) {
        f32x4 o4;
#pragma unroll
        for (int j = 0; j < 4; ++j) o4[j] = e[j] / s;
        *(f32x4*)&p[idx] = o4;
    }
}

// ================= transpose V (f32) =================
__global__ __launch_bounds__(256)
void transpose64f(const float* src, int sld, long sSo, long sSi, int sDiv, float* dst, int Skv)
{
    const int z = blockIdx.y;
    const float* Sp = src + (long)(z / sDiv) * sSo + (long)(z % sDiv) * sSi;
    float* Dp = dst + (long)z * 64 * Skv;
    const int j0 = blockIdx.x * 64;
    __shared__ float tl[64][68];
    const int tid = threadIdx.x;
#pragma unroll
    for (int it = 0; it < 4; ++it) {
        int e = (it * 256 + tid) * 4;
        int r = e >> 6, c = e & 63;
        f32x4 d = *(const f32x4*)&Sp[(long)(j0 + r) * sld + c];
        *(f32x4*)&tl[r][c] = d;
    }
    __syncthreads();
    const int d0 = tid >> 2;
    const int jc = (tid & 3) * 16;
    float tmp[16];
#pragma unroll
    for (int i = 0; i < 16; ++i) tmp[i] = tl[jc + i][d0];
#pragma unroll
    for (int i = 0; i < 16; ++i) Dp[(long)d0 * Skv + j0 + jc + i] = tmp[i];
}

// ================= PV K-split partial reduce: xn += sum of 4 partials =================
__global__ __launch_bounds__(256)
void pvred(const float* pp, float* xn, int g)
{
    const long i = (long)blockIdx.x * 256 + threadIdx.x;   // 0..524287 f32x4 groups
    const long e = i * 4;
    const int z = (int)(e >> 16);
    const int rem = (int)(e & 65535);
    const int row = rem >> 6;
    const int col = rem & 63;
    f32x4 a = *(const f32x4*)&pp[e];
    f32x4 b = *(const f32x4*)&pp[2097152 + e];
    f32x4 c = *(const f32x4*)&pp[2 * 2097152 + e];
    f32x4 d = *(const f32x4*)&pp[3 * 2097152 + e];
    f32x4 s;
#pragma unroll
    for (int j = 0; j < 4; ++j) s[j] = (a[j] + b[j]) + (c[j] + d[j]);
    float* dst = xn + (long)g * 2097152 + (long)(z >> 4) * 1048576
               + (long)row * 1024 + (z & 15) * 64 + col;
    *(f32x4*)dst = s;
}

// ================= router: f64 logits, top2 -> combine + tagged per-expert lists =================
__global__ __launch_bounds__(256)
void router_k(const float* xn2, const float* rw, const float* rb, float* cmb,
              int* cnt, int* tlist)
{
    const int tok = blockIdx.x * 4 + (threadIdx.x >> 6);
    const int lane = threadIdx.x & 63;
    const float* xp = xn2 + (long)tok * 1024 + lane * 16;
    float xv[16];
#pragma unroll
    for (int j = 0; j < 16; ++j) xv[j] = xp[j];
    double acc[8];
#pragma unroll
    for (int e = 0; e < 8; ++e) {
        const float* wp = rw + e * 1024 + lane * 16;
        double s = 0.0;
#pragma unroll
        for (int j = 0; j < 16; ++j) s += (double)xv[j] * (double)wp[j];
        acc[e] = s;
    }
    for (int o = 32; o; o >>= 1) {
#pragma unroll
        for (int e = 0; e < 8; ++e) acc[e] += __shfl_xor(acc[e], o);
    }
    if (lane == 0) {
        double l[8];
#pragma unroll
        for (int e = 0; e < 8; ++e) l[e] = acc[e] + (double)rb[e];
        int i1 = 0;
#pragma unroll
        for (int e = 1; e < 8; ++e) if (l[e] > l[i1]) i1 = e;
        int i2 = (i1 == 0) ? 1 : 0;
#pragma unroll
        for (int e = 0; e < 8; ++e) if (e != i1 && l[e] > l[i2]) i2 = e;
        double w1 = 1.0 / (1.0 + exp(l[i2] - l[i1]));
        double w2 = 1.0 - w1;
        float c8[8] = {0, 0, 0, 0, 0, 0, 0, 0};
        c8[i1] = (float)w1;
        c8[i2] = (float)w2;
        float* cp = cmb + (long)tok * 8;
#pragma unroll
        for (int e = 0; e < 8; ++e) cp[e] = c8[e];
        int s1 = atomicAdd(&cnt[i1], 1);
        tlist[i1 * 8192 + s1] = tok;              // k=0
        int s2 = atomicAdd(&cnt[i2], 1);
        tlist[i2 * 8192 + s2] = tok | 65536;      // k=1
    }
}

// exclusive prefix over 8 counts
__global__ void prefix8(const int* cnt, int* pfx)
{
    if (threadIdx.x == 0) {
        int s = 0;
#pragma unroll
        for (int e = 0; e < 8; ++e) { pfx[e] = s; s += cnt[e]; }
    }
}

// gather all experts: XE[pfx[e]+slot] = bf16((xn2[tok]-m)*rstd*w_e + b_e)
__global__ __launch_bounds__(256)
void gather_all(const float* xn2, const float* st, const int* cnt, const int* pfx,
                const int* tlist, const float* lnw, const float* lnb, u16* xe)
{
    const int e = blockIdx.y;
    const int slot = blockIdx.x;
    if (slot >= cnt[e]) return;
    const int tok = tlist[e * 8192 + slot] & 0xFFFF;
    const int c0 = threadIdx.x * 4;
    f32x4 v = *(const f32x4*)&xn2[(long)tok * 1024 + c0];
    const float m = st[tok * 2], r = st[tok * 2 + 1];
    const float* w = lnw + (long)e * 1024;
    const float* b = lnb + (long)e * 1024;
    short4v o4;
#pragma unroll
    for (int j = 0; j < 4; ++j) o4[j] = (short)f2b((v[j] - m) * r * w[c0 + j] + b[c0 + j]);
    *(short4v*)&xe[(long)(pfx[e] + slot) * 1024 + c0] = o4;
}

// ================= grid-stride f32 -> bf16 weight conversion =================
__global__ __launch_bounds__(256)
void cvtw(const float* in, u16* out, long n4)
{
    const long stride = (long)gridDim.x * 256;
    for (long i = (long)blockIdx.x * 256 + threadIdx.x; i < n4; i += stride) {
        f32x4 v = *(const f32x4*)&in[i * 4];
        short4v o;
#pragma unroll
        for (int j = 0; j < 4; ++j) o[j] = (short)f2b(v[j]);
        *(short4v*)&out[i * 4] = o;
    }
}

extern "C" void kernel_launch(void* const* d_in, const int* in_sizes, int n_in,
                              void* d_out, int out_size, void* d_ws, size_t ws_size,
                              hipStream_t stream)
{
    (void)in_sizes; (void)n_in; (void)out_size;
    const float* x          = (const float*)d_in[0];
    const float* modal      = (const float*)d_in[1];
    const float* attn_in_w  = (const float*)d_in[2];
    const float* attn_in_b  = (const float*)d_in[3];
    const float* attn_out_w = (const float*)d_in[4];
    const float* attn_out_b = (const float*)d_in[5];
    const float* xattn_in_w = (const float*)d_in[6];
    const float* xattn_in_b = (const float*)d_in[7];
    const float* xattn_out_w= (const float*)d_in[8];
    const float* xattn_out_b= (const float*)d_in[9];
    const float* norm1_w = (const float*)d_in[10];
    const float* norm1_b = (const float*)d_in[11];
    const float* norm2_w = (const float*)d_in[12];
    const float* norm2_b = (const float*)d_in[13];
    const float* norm3_w = (const float*)d_in[14];
    const float* norm3_b = (const float*)d_in[15];
    const float* xnorm_w = (const float*)d_in[16];
    const float* xnorm_b = (const float*)d_in[17];
    const float* router_w = (const float*)d_in[18];
    const float* router_b = (const float*)d_in[19];
    const float* gate_w = (const float*)d_in[20];
    const float* gate_b = (const float*)d_in[21];
    const float* exp_ln_w = (const float*)d_in[22];
    const float* exp_ln_b = (const float*)d_in[23];
    const float* exp_fc1_w = (const float*)d_in[24];
    const float* exp_fc1_b = (const float*)d_in[25];
    const float* exp_fc2_w = (const float*)d_in[26];
    const float* exp_fc2_b = (const float*)d_in[27];

    char* wsb = (char*)d_ws;
    size_t off = 0;
    auto AL = [&](size_t bytes) { size_t r = off; off += (bytes + 255) & ~(size_t)255; return r; };
    float* XN  = (float*)(wsb + AL(33554432));   // 8192x1024 f32; MoE phase: bf16 weight store (with H)
    float* H   = (float*)(wsb + AL(33554432));
    float* H2  = (float*)(wsb + AL(33554432));   // attn phase: self-scores region (H2..MOE = 128MiB)
    float* XN2 = (float*)(wsb + AL(33554432));
    float* FUS = (float*)(wsb + AL(33554432));
    float* MOE = (float*)(wsb + AL(33554432));
    float* XKV = (float*)(wsb + AL(8388608));    // 1024x2048 f32
    float* CMB = (float*)(wsb + AL(262144));     // 8192x8 f32
    float* ST  = (float*)(wsb + AL(65536));      // 8192x2 f32
    int*   CNT = (int*)(wsb + AL(256));          // 8 ints
    int*   PFX = (int*)(wsb + AL(256));          // 8 ints
    int*   TLS = (int*)(wsb + AL(262144));       // 8x8192 ints (tok | k<<16)
    char*  RA  = wsb + AL(100663296);            // 96MB  } contiguous 192MB region
    char*  RB  = wsb + AL(100663296);            // 96MB  }
    if (off > ws_size) return;                   // loud failure

    float* QKV = (float*)RA;                     // [8192,3072]
    float* XQ  = (float*)RA;                     // [8192,1024]
    float* XO  = (float*)(RA + 33554432);        // [8192,1024]
    float* SCf = (float*)RB;                     // cross scores (64MB)
    float* PP  = (float*)RB;                     // PV partials [4][32][1024][64] f32 = 32MB (self-attn phase)
    float* VTf = (float*)(RB + 67108864);        // V^T (32MB)
    float* SC2 = H2;                             // self scores: 32bh x 1024 x 1024 f32 (H2..MOE dead)
    u16*   HH  = (u16*)RA;                       // MoE phase
    u16*   XE  = (u16*)(RA + 135266304);
    u16*   WB  = (u16*)XN;                       // 64MB bf16 weight buffer (MoE phase, XN∪H dead)
    float* out = (float*)d_out;

    // 1) ln1 = LN(x, norm1) -> XN
    ln2p<0><<<8192, 256, 0, stream>>>(x, nullptr, nullptr, norm1_w, norm1_b, XN);

    // 2) qkv = ln1 @ attn_in_w^T + b -> QKV
    {
        EGemmP p{XN, 1024, 0, 0, 1, attn_in_w, 1024, 0, 0, 1,
                 QKV, 3072, 0, 0, 1, attn_in_b, nullptr, nullptr, 1024};
        gemm_emu<0, 2, 2, 4, 2><<<dim3(64, 48, 1), 256, 0, stream>>>(p);
    }
    // 2b) self V -> VTf[bh][64][1024]
    transpose64f<<<dim3(16, 128), 256, 0, stream>>>(QKV + 2048, 3072, (long)1024 * 3072, 64, 16, VTf, 1024);

    // 3) self-attention in 4 chunks of 32 bh; scores in SC2; PV K-split x4 into PP then reduce
    for (int g = 0; g < 4; ++g) {
        EGemmP s{QKV + (long)g * 2 * 1024 * 3072, 3072, (long)1024 * 3072, 64, 16,
                 QKV + 1024 + (long)g * 2 * 1024 * 3072, 3072, (long)1024 * 3072, 64, 16,
                 SC2, 1024, 0, (long)1024 * 1024, 1 << 20, nullptr, nullptr, nullptr, 64};
        gemm_emu<0, 2, 2, 4, 2><<<dim3(8, 16, 32), 256, 0, stream>>>(s);

        softmax_f32<<<32 * 1024, 256, 0, stream>>>(SC2, 1024, 0.125f);

        EGemmP v{SC2, 1024, 256, (long)1024 * 1024, 32,
                 VTf + (long)g * 32 * 64 * 1024, 1024, 256, (long)64 * 1024, 32,
                 PP, 64, 2097152, 65536, 32, nullptr, nullptr, nullptr, 256};
        gemm_emu<0, 2, 2, 2, 2><<<dim3(16, 1, 128), 256, 0, stream>>>(v);

        pvred<<<2048, 256, 0, stream>>>(PP, XN, g);
    }

    // 4) h = x + o @ attn_out_w^T + b -> H
    {
        EGemmP p{XN, 1024, 0, 0, 1, attn_out_w, 1024, 0, 0, 1,
                 H, 1024, 0, 0, 1, attn_out_b, x, nullptr, 1024};
        gemm_emu<1, 2, 2, 4, 2><<<dim3(64, 16, 1), 256, 0, stream>>>(p);
    }
    // 5) xn = LN(h, xnorm) -> XN
    ln2p<0><<<8192, 256, 0, stream>>>(H, nullptr, nullptr, xnorm_w, xnorm_b, XN);

    // 6) xq = xn @ xattn_in_w[0:E]^T + b -> XQ
    {
        EGemmP p{XN, 1024, 0, 0, 1, xattn_in_w, 1024, 0, 0, 1,
                 XQ, 1024, 0, 0, 1, xattn_in_b, nullptr, nullptr, 1024};
        gemm_emu<0, 2, 2, 4, 2><<<dim3(64, 16, 1), 256, 0, stream>>>(p);
    }
    // 7) xkv = modal @ xattn_in_w[E:3E]^T + b -> XKV
    {
        EGemmP p{modal, 1024, 0, 0, 1, xattn_in_w + (size_t)1024 * 1024, 1024, 0, 0, 1,
                 XKV, 2048, 0, 0, 1, xattn_in_b + 1024, nullptr, nullptr, 1024};
        gemm_emu<0, 2, 2, 4, 2><<<dim3(8, 32, 1), 256, 0, stream>>>(p);
    }
    // 7b) cross V -> VTf[bh][64][128]
    transpose64f<<<dim3(2, 128), 256, 0, stream>>>(XKV + 1024, 2048, (long)128 * 2048, 64, 16, VTf, 128);

    // 8) cross scores -> SCf
    {
        EGemmP s{XQ, 1024, (long)1024 * 1024, 64, 16,
                 XKV, 2048, (long)128 * 2048, 64, 16,
                 SCf, 128, 0, (long)1024 * 128, 1 << 20, nullptr, nullptr, nullptr, 64};
        gemm_emu<0, 2, 2, 4, 2><<<dim3(8, 2, 128), 256, 0, stream>>>(s);
    }
    softmax_f32<<<128 * 1024, 256, 0, stream>>>(SCf, 128, 0.125f);
    // 9) xo = P @ V -> XO
    {
        EGemmP v{SCf, 128, 0, (long)1024 * 128, 1 << 20,
                 VTf, 128, 0, (long)64 * 128, 1 << 20,
                 XO, 1024, (long)1024 * 1024, 64, 16, nullptr, nullptr, nullptr, 128};
        gemm_emu<0, 2, 2, 4, 2><<<dim3(8, 1, 128), 256, 0, stream>>>(v);
    }
    // 10) fusion = xo @ xattn_out_w^T + b -> FUS
    {
        EGemmP p{XO, 1024, 0, 0, 1, xattn_out_w, 1024, 0, 0, 1,
                 FUS, 1024, 0, 0, 1, xattn_out_b, nullptr, nullptr, 1024};
        gemm_emu<0, 2, 2, 4, 2><<<dim3(64, 16, 1), 256, 0, stream>>>(p);
    }
    // 11) h2 = h + sigmoid(xn @ gate_w^T + gate_b) * fusion -> H2
    {
        EGemmP p{XN, 1024, 0, 0, 1, gate_w, 1024, 0, 0, 1,
                 H2, 1024, 0, 0, 1, gate_b, H, FUS, 1024};
        gemm_emu<2, 2, 2, 4, 2><<<dim3(64, 16, 1), 256, 0, stream>>>(p);
    }
    // 12) xn2 = LN(h2, norm2); rowstats (+cnt zero); router; prefix
    ln2p<0><<<8192, 256, 0, stream>>>(H2, nullptr, nullptr, norm2_w, norm2_b, XN2);
    rowstats<<<8192, 256, 0, stream>>>(XN2, ST, CNT);
    router_k<<<2048, 256, 0, stream>>>(XN2, router_w, router_b, CMB, CNT, TLS);
    prefix8<<<1, 64, 0, stream>>>(CNT, PFX);

    // 13) sparse experts: gather_all -> cvt fc1 wts -> fc1 -> cvt fc2 wts -> fc2
    gather_all<<<dim3(8192, 8), 256, 0, stream>>>(XN2, ST, CNT, PFX, TLS, exp_ln_w, exp_ln_b, XE);
    cvtw<<<2048, 256, 0, stream>>>(exp_fc1_w, WB, 8388608);   // 8x4096x1024
    {
        MoeP p1{XE, 1024, WB, (long)4096 * 1024, 1024,
                HH, nullptr, nullptr, 4096,
                exp_fc1_b, 4096, nullptr, CNT, PFX, TLS, 1024};
        gemm_moe<3, 4><<<dim3(64, 32, 8), 256, 0, stream>>>(p1);
    }
    cvtw<<<2048, 256, 0, stream>>>(exp_fc2_w, WB, 8388608);   // 8x1024x4096
    {
        MoeP p2{HH, 4096, WB, (long)1024 * 4096, 4096,
                nullptr, MOE, FUS, 1024,
                exp_fc2_b, 1024, CMB, CNT, PFX, TLS, 4096};
        gemm_moe<4, 2><<<dim3(64, 16, 8), 256, 0, stream>>>(p2);
    }

    // 14) out = LN(h2 + moe1 + moe2, norm3) -> f32 d_out
    ln2p<2><<<8192, 256, 0, stream>>>(H2, MOE, FUS, norm3_w, norm3_b, out);
}